// Round 8
// baseline (3065.028 us; speedup 1.0000x reference)
//
#include <hip/hip_runtime.h>

#define NA 20000
#define NE 320000
#define FD 128
#define NRBF 20
#define NL 3
#define PI_F 3.14159265358979323846f

typedef __attribute__((ext_vector_type(8))) short bf16x8;
typedef __attribute__((ext_vector_type(4))) float f32x4;

// ---------------- module-static device scratch ----------------
__device__ float g_unitv[NE*3];
__device__ float g_env[NE];
__device__ float g_rbf[NE*NRBF];
__device__ float g_s[NA*FD];
__device__ float g_vA[NA*3*FD];
__device__ float g_vB[NA*3*FD];
__device__ float g_phi[NA*3*FD];        // phi, later reused as u_v
__device__ float g_vv[NA*3*FD];
__device__ float g_stk[NA*2*FD];
__device__ float g_hsm[NA*FD];
__device__ int   g_off[NA+1];
__device__ int   g_cur[NA];
__device__ int   g_eid[NE];
__device__ unsigned short g_sb[NL*NA*FD];        // bf16 s snapshots per layer
// packed bf16 weights (MFMA B-fragment order)
__device__ unsigned short g_w1p[NL*FD*2*FD];     // edge_w1: K=128,N=256
__device__ unsigned short g_w2p[NL*2*FD*FD];     // edge_w2: K=256,N=128
__device__ unsigned short g_rw1p[FD*2*FD];       // ro_w1:   K=128,N=256

__device__ __forceinline__ float swishf(float x) { return x / (1.0f + __expf(-x)); }
__device__ __forceinline__ unsigned short f2bf(float x) {
    unsigned int u = __float_as_uint(x);
    unsigned int r = (u + 0x7FFFu + ((u >> 16) & 1u)) >> 16;
    return (unsigned short)r;
}
__device__ __forceinline__ float bf2f(unsigned short u) {
    return __uint_as_float(((unsigned int)u) << 16);
}

// ---------------- geometry ----------------
__global__ __launch_bounds__(256) void k_geom(const float* __restrict__ xyz, const int* __restrict__ nbrs)
{
    int e = blockIdx.x * 256 + threadIdx.x;
    if (e >= NE) return;
    int si = nbrs[2*e], di = nbrs[2*e+1];
    float rx = xyz[3*di+0] - xyz[3*si+0];
    float ry = xyz[3*di+1] - xyz[3*si+1];
    float rz = xyz[3*di+2] - xyz[3*si+2];
    float d2 = rx*rx + ry*ry + rz*rz + 3e-15f;
    float dist = sqrtf(d2);
    float inv = 1.0f / dist;
    g_unitv[3*e+0] = rx*inv;
    g_unitv[3*e+1] = ry*inv;
    g_unitv[3*e+2] = rz*inv;
    g_env[e] = (dist < 5.0f) ? 0.5f*(cosf(PI_F*dist*0.2f) + 1.0f) : 0.0f;
    #pragma unroll
    for (int k = 0; k < NRBF; ++k)
        g_rbf[(size_t)e*NRBF + k] = sinf((float)(k+1) * (PI_F*0.2f) * dist) * inv;
}

// ---------------- init ----------------
__global__ __launch_bounds__(256) void k_embed(const int* __restrict__ z, const float* __restrict__ table)
{
    int idx = blockIdx.x * 256 + threadIdx.x;
    if (idx >= NA * FD) return;
    int n = idx >> 7, f = idx & 127;
    g_s[idx] = table[z[n]*FD + f];
}

__global__ __launch_bounds__(256) void k_zero(float* __restrict__ fout)
{
    int idx = blockIdx.x * 256 + threadIdx.x;
    if (idx < NA*3*FD) g_vA[idx] = 0.f;
    if (idx < NA)      g_cur[idx] = 0;
    if (idx < NA*3)    fout[idx] = 0.f;
}

// ---------------- snapshot s (fp32 -> bf16) after layer l ----------------
__global__ __launch_bounds__(256) void k_snap(int l)
{
    int idx = blockIdx.x * 256 + threadIdx.x;
    if (idx < NA*FD) g_sb[(size_t)l*NA*FD + idx] = f2bf(g_s[idx]);
}

// ---------------- weight pack: row-major W(K,N) -> MFMA B-fragment order ----------------
// REQUIRES grid*block == (K>>5)*(N>>4)*64 threads (see packGrid() below).
// Round 6/7 bug: launched half the grid for the 256-wide matrices -> half the
// packed weights stayed zero -> absmax ~4.5. Grid is now computed, not hand-set.
__global__ __launch_bounds__(256) void k_pack(const float* __restrict__ W, unsigned short* __restrict__ out,
                                              int K, int N)
{
    int idx = blockIdx.x * 256 + threadIdx.x;
    int total = (K >> 5) * (N >> 4) * 64;
    if (idx >= total) return;
    int lane = idx & 63;
    int kc = (idx >> 6) % (K >> 5);
    int nt = (idx >> 6) / (K >> 5);
    int col = nt*16 + (lane & 15);
    int kb  = kc*32 + (lane >> 4) * 8;
    bf16x8 v;
    #pragma unroll
    for (int j = 0; j < 8; ++j) v[j] = (short)f2bf(W[(size_t)(kb + j) * N + col]);
    *reinterpret_cast<bf16x8*>(out + (size_t)idx * 8) = v;
}

// ---------------- CSR build ----------------
__global__ __launch_bounds__(256) void k_count(const int* __restrict__ nbrs)
{
    int e = blockIdx.x * 256 + threadIdx.x;
    if (e < NE) atomicAdd(&g_cur[nbrs[2*e]], 1);
}

__global__ __launch_bounds__(1024) void k_scan()
{
    __shared__ int sd[1024];
    __shared__ int sbase;
    int tid = threadIdx.x;
    if (tid == 0) sbase = 0;
    __syncthreads();
    for (int c0 = 0; c0 < NA; c0 += 1024) {
        int i = c0 + tid;
        int x = (i < NA) ? g_cur[i] : 0;
        sd[tid] = x;
        __syncthreads();
        for (int o = 1; o < 1024; o <<= 1) {
            int t = (tid >= o) ? sd[tid - o] : 0;
            __syncthreads();
            sd[tid] += t;
            __syncthreads();
        }
        if (i < NA) { int excl = sbase + sd[tid] - x; g_off[i] = excl; g_cur[i] = excl; }
        __syncthreads();
        if (tid == 0) sbase += sd[1023];
        __syncthreads();
    }
    if (tid == 0) g_off[NA] = sbase;
}

__global__ __launch_bounds__(256) void k_fill(const int* __restrict__ nbrs)
{
    int e = blockIdx.x * 256 + threadIdx.x;
    if (e < NE) { int p = atomicAdd(&g_cur[nbrs[2*e]], 1); g_eid[p] = e; }
}

// ---------------- generic fp32 GEMM (node matmuls) ----------------
#define BM 128
#define BN 128
#define BK 32
#define LDA_S 132
#define LDW_S 132
template<bool SWISH>
__global__ __launch_bounds__(256) void k_gemm(const float* __restrict__ A, const float* __restrict__ W,
        const float* __restrict__ bias, float* __restrict__ C, int R, int K, int Cc)
{
    __shared__ float As[BK * LDA_S];
    __shared__ float Ws[BK * LDW_S];
    int tid = threadIdx.x;
    int row0 = blockIdx.x * BM;
    int col0 = blockIdx.y * BN;
    int tx = tid & 15, ty = tid >> 4;
    float acc[8][8];
    #pragma unroll
    for (int i = 0; i < 8; ++i)
        #pragma unroll
        for (int j = 0; j < 8; ++j) acc[i][j] = 0.f;
    for (int k0 = 0; k0 < K; k0 += BK) {
        #pragma unroll
        for (int i = 0; i < 4; ++i) {
            int fi = tid + i*256;
            int r = fi >> 3, q = fi & 7;
            float4 v = make_float4(0.f, 0.f, 0.f, 0.f);
            int gr = row0 + r;
            if (gr < R) v = *reinterpret_cast<const float4*>(A + (size_t)gr*K + k0 + q*4);
            As[(q*4+0)*LDA_S + r] = v.x;
            As[(q*4+1)*LDA_S + r] = v.y;
            As[(q*4+2)*LDA_S + r] = v.z;
            As[(q*4+3)*LDA_S + r] = v.w;
        }
        #pragma unroll
        for (int i = 0; i < 4; ++i) {
            int fi = tid + i*256;
            int kr = fi >> 5, qq = fi & 31;
            float4 v = *reinterpret_cast<const float4*>(W + (size_t)(k0+kr)*Cc + col0 + qq*4);
            *reinterpret_cast<float4*>(&Ws[kr*LDW_S + qq*4]) = v;
        }
        __syncthreads();
        #pragma unroll
        for (int k = 0; k < BK; ++k) {
            float a[8], w[8];
            *reinterpret_cast<float4*>(&a[0]) = *reinterpret_cast<const float4*>(&As[k*LDA_S + ty*8]);
            *reinterpret_cast<float4*>(&a[4]) = *reinterpret_cast<const float4*>(&As[k*LDA_S + ty*8 + 4]);
            *reinterpret_cast<float4*>(&w[0]) = *reinterpret_cast<const float4*>(&Ws[k*LDW_S + tx*8]);
            *reinterpret_cast<float4*>(&w[4]) = *reinterpret_cast<const float4*>(&Ws[k*LDW_S + tx*8 + 4]);
            #pragma unroll
            for (int i = 0; i < 8; ++i)
                #pragma unroll
                for (int j = 0; j < 8; ++j)
                    acc[i][j] = fmaf(a[i], w[j], acc[i][j]);
        }
        __syncthreads();
    }
    #pragma unroll
    for (int i = 0; i < 8; ++i) {
        int gr = row0 + ty*8 + i;
        if (gr >= R) continue;
        #pragma unroll
        for (int j = 0; j < 8; j += 4) {
            int gc = col0 + tx*8 + j;
            float t[4];
            #pragma unroll
            for (int jj = 0; jj < 4; ++jj) {
                float x = acc[i][j+jj] + (bias ? bias[gc+jj] : 0.f);
                t[jj] = SWISH ? swishf(x) : x;
            }
            float4 o; o.x=t[0]; o.y=t[1]; o.z=t[2]; o.w=t[3];
            *reinterpret_cast<float4*>(C + (size_t)gr*Cc + gc) = o;
        }
    }
}

// ---------------- message: per-node CSR gather ----------------
__global__ __launch_bounds__(128) void k_msg(
        const int* __restrict__ nbrs,
        const float* __restrict__ dw, const float* __restrict__ db,
        const float* __restrict__ vold, float* __restrict__ vnew)
{
    int n = blockIdx.x;
    int f = threadIdx.x;
    float sacc = 0.f, va0 = 0.f, va1 = 0.f, va2 = 0.f;
    int b = g_off[n], eend = g_off[n+1];
    float db0 = db[f], db1 = db[FD + f], db2 = db[2*FD + f];
    for (int ii = b; ii < eend; ++ii) {
        int e = g_eid[ii];
        int dst = nbrs[2*e+1];
        float ev = g_env[e];
        float rb[NRBF];
        const float4* rp = reinterpret_cast<const float4*>(g_rbf + (size_t)e*NRBF);
        #pragma unroll
        for (int q = 0; q < 5; ++q) { float4 t = rp[q]; rb[4*q]=t.x; rb[4*q+1]=t.y; rb[4*q+2]=t.z; rb[4*q+3]=t.w; }
        float w0 = db0, w1 = db1, w2 = db2;
        #pragma unroll
        for (int k = 0; k < NRBF; ++k) {
            float r = rb[k];
            w0 = fmaf(r, dw[k*3*FD + f],        w0);
            w1 = fmaf(r, dw[k*3*FD + FD + f],   w1);
            w2 = fmaf(r, dw[k*3*FD + 2*FD + f], w2);
        }
        w0 *= ev; w1 *= ev; w2 *= ev;
        const float* pd = g_phi + (size_t)dst*3*FD;
        float p0 = pd[f]        * w0;
        float p1 = pd[FD + f]   * w1;
        float p2 = pd[2*FD + f] * w2;
        sacc += p1;
        float ux = g_unitv[3*e+0], uy = g_unitv[3*e+1], uz = g_unitv[3*e+2];
        const float* vd = vold + (size_t)dst*3*FD;
        va0 = fmaf(p2, ux, fmaf(p0, vd[f],        va0));
        va1 = fmaf(p2, uy, fmaf(p0, vd[FD + f],   va1));
        va2 = fmaf(p2, uz, fmaf(p0, vd[2*FD + f], va2));
    }
    size_t nb = (size_t)n*3*FD;
    vnew[nb + f]        = vold[nb + f]        + va0;
    vnew[nb + FD + f]   = vold[nb + FD + f]   + va1;
    vnew[nb + 2*FD + f] = vold[nb + 2*FD + f] + va2;
    g_s[n*FD + f] += sacc;
}

// ---------------- stack = [s, vnorm(v_v)] ----------------
__global__ __launch_bounds__(256) void k_stack()
{
    int idx = blockIdx.x * 256 + threadIdx.x;
    if (idx >= NA * FD) return;
    int n = idx >> 7, f = idx & 127;
    const float* v = g_vv + (size_t)n*3*FD;
    float a = v[f], b = v[FD + f], c = v[2*FD + f];
    float vn = sqrtf(a*a + b*b + c*c + 3e-15f);
    g_stk[(size_t)n*2*FD + f]      = g_s[idx];
    g_stk[(size_t)n*2*FD + FD + f] = vn;
}

// ---------------- apply update ----------------
__global__ __launch_bounds__(256) void k_apply(const float* __restrict__ split, float* __restrict__ v)
{
    int idx = blockIdx.x * 256 + threadIdx.x;
    if (idx >= NA * FD) return;
    int n = idx >> 7, f = idx & 127;
    const float* sp = split + (size_t)n*3*FD;
    float avv = sp[f], asv = sp[FD + f], ass = sp[2*FD + f];
    size_t nb = (size_t)n*3*FD;
    float dot = 0.f;
    #pragma unroll
    for (int d = 0; d < 3; ++d) {
        float u = g_phi[nb + d*FD + f], w = g_vv[nb + d*FD + f];
        v[nb + d*FD + f] += u * avv;
        dot = fmaf(u, w, dot);
    }
    g_s[idx] += dot * asv + ass;
}

// ================= FUSED edge pipeline (low-LDS, 2-barrier) =================
// Block = 64 edges, 4 waves x 16 edges. acc_e in VGPRs (8 x f32x4, C-layout).
// A-fragments gathered DIRECTLY from g_sb per lane (no pair staging, no barrier).
// hid = 64x128 bf16 (16 KB): GEMM1/GEMM2 interleaved in two K-halves; rows are
// wave-private -> no barriers in the layer loop. einit stages rbf/env/de_w into
// the hid region (aliased), protected by the only 2 barriers in the kernel.
__global__ __launch_bounds__(256) void k_edge_fused(
        const int* __restrict__ nbrs,
        const float* __restrict__ de_w, const float* __restrict__ de_b,
        const float* __restrict__ eb1, const float* __restrict__ eb2,
        const float* __restrict__ ro_b1, const float* __restrict__ ro_w2,
        const float* __restrict__ ro_b2, float* __restrict__ fatom)
{
    __shared__ unsigned short hid[64*128];   // 16 KB (aliased by einit staging)
    int tid = threadIdx.x;
    int e0 = blockIdx.x * 64;
    int lane = tid & 63, w = tid >> 6;
    int r0 = w * 16;
    int arow = r0 + (lane & 15);
    int crow = r0 + ((lane >> 4) << 2);
    int ccol = lane & 15;

    float* rbfL  = reinterpret_cast<float*>(hid);   // 64*20 floats
    float* envL  = rbfL + 64*NRBF;                  // 64 floats
    float* de_wL = envL + 64;                       // 20*128 floats (total 15616 B)

    #pragma unroll
    for (int i = 0; i < 5; ++i) {
        int j = i*256 + tid;
        if (j < 64*NRBF) rbfL[j] = g_rbf[(size_t)e0*NRBF + j];
    }
    if (tid < 64) envL[tid] = g_env[e0 + tid];
    #pragma unroll
    for (int i = 0; i < 10; ++i) de_wL[i*256 + tid] = de_w[i*256 + tid];
    __syncthreads();

    // ---- einit into acc_e (C-layout: row=crow+i, col=nt*16+ccol) ----
    f32x4 acc_e[8];
    #pragma unroll
    for (int nt = 0; nt < 8; ++nt) acc_e[nt] = f32x4{0.f, 0.f, 0.f, 0.f};
    #pragma unroll 4
    for (int k = 0; k < NRBF; ++k) {
        float rb[4];
        #pragma unroll
        for (int i = 0; i < 4; ++i) rb[i] = rbfL[(crow + i)*NRBF + k];
        #pragma unroll
        for (int nt = 0; nt < 8; ++nt) {
            float wv = de_wL[k*FD + nt*16 + ccol];
            #pragma unroll
            for (int i = 0; i < 4; ++i) acc_e[nt][i] = fmaf(rb[i], wv, acc_e[nt][i]);
        }
    }
    #pragma unroll
    for (int nt = 0; nt < 8; ++nt) {
        float bb = de_b[nt*16 + ccol];
        #pragma unroll
        for (int i = 0; i < 4; ++i) acc_e[nt][i] = (acc_e[nt][i] + bb) * envL[crow + i];
    }
    __syncthreads();   // einit reads of shared staging done before hid overwrite

    // per-lane gather node indices (row = arow)
    int ga = e0 + arow;
    int siA = nbrs[2*ga], diA = nbrs[2*ga+1];

    // ---- 3 edge-MLP layers ----
    for (int l = 0; l < NL; ++l) {
        const unsigned short* sb = g_sb + (size_t)l*NA*FD;
        const unsigned short* w1l = g_w1p + (size_t)l*FD*2*FD;
        const unsigned short* w2l = g_w2p + (size_t)l*2*FD*FD;
        const float* b1l = eb1 + (size_t)l*2*FD;
        const float* b2l = eb2 + (size_t)l*FD;

        // A-fragments: pair = s[src]+s[dst], direct from global
        bf16x8 a1f[4];
        #pragma unroll
        for (int kc = 0; kc < 4; ++kc) {
            bf16x8 aS = *reinterpret_cast<const bf16x8*>(sb + (size_t)siA*FD + kc*32 + (lane >> 4)*8);
            bf16x8 aD = *reinterpret_cast<const bf16x8*>(sb + (size_t)diA*FD + kc*32 + (lane >> 4)*8);
            #pragma unroll
            for (int j = 0; j < 8; ++j)
                a1f[kc][j] = (short)f2bf(bf2f((unsigned short)aS[j]) + bf2f((unsigned short)aD[j]));
        }
        // two K-halves: GEMM1 (8 nt tiles) -> hid -> GEMM2 (4 kc chunks)
        #pragma unroll
        for (int half = 0; half < 2; ++half) {
            #pragma unroll
            for (int nt2 = 0; nt2 < 8; ++nt2) {
                int nt = half*8 + nt2;
                f32x4 acc = f32x4{0.f, 0.f, 0.f, 0.f};
                #pragma unroll
                for (int kc = 0; kc < 4; ++kc) {
                    bf16x8 bv = *reinterpret_cast<const bf16x8*>(w1l + ((size_t)(nt*4 + kc)*64 + lane)*8);
                    acc = __builtin_amdgcn_mfma_f32_16x16x32_bf16(a1f[kc], bv, acc, 0, 0, 0);
                }
                int col = nt*16 + ccol;
                float bb = b1l[col];
                int colh = col - half*128;
                #pragma unroll
                for (int i = 0; i < 4; ++i) {
                    int row = crow + i;
                    float h = swishf(acc[i] + bb);
                    int byte = (row*256 + colh*2) ^ ((row & 7) << 4);
                    *reinterpret_cast<unsigned short*>(reinterpret_cast<char*>(hid) + byte) = f2bf(h);
                }
            }
            // wave-private rows -> no barrier; consume this half's 4 K-chunks
            #pragma unroll
            for (int kc2 = 0; kc2 < 4; ++kc2) {
                int byte = (arow*256 + kc2*64 + (lane >> 4)*16) ^ ((arow & 7) << 4);
                bf16x8 a2 = *reinterpret_cast<const bf16x8*>(reinterpret_cast<const char*>(hid) + byte);
                int kc = half*4 + kc2;
                #pragma unroll
                for (int nt2 = 0; nt2 < 8; ++nt2) {
                    bf16x8 bv = *reinterpret_cast<const bf16x8*>(w2l + ((size_t)(nt2*8 + kc)*64 + lane)*8);
                    acc_e[nt2] = __builtin_amdgcn_mfma_f32_16x16x32_bf16(a2, bv, acc_e[nt2], 0, 0, 0);
                }
            }
        }
        #pragma unroll
        for (int nt2 = 0; nt2 < 8; ++nt2) {
            float bb = b2l[nt2*16 + ccol];
            #pragma unroll
            for (int i = 0; i < 4; ++i) acc_e[nt2][i] += bb;
        }
    }

    // ---- readout: dump acc_e -> bf16 A-tile (wave-private rows), GEMM1 + in-register dot ----
    #pragma unroll
    for (int nt = 0; nt < 8; ++nt) {
        int col = nt*16 + ccol;
        #pragma unroll
        for (int i = 0; i < 4; ++i) {
            int row = crow + i;
            int byte = (row*256 + col*2) ^ ((row & 7) << 4);
            *reinterpret_cast<unsigned short*>(reinterpret_cast<char*>(hid) + byte) = f2bf(acc_e[nt][i]);
        }
    }
    bf16x8 af[4];
    #pragma unroll
    for (int kc = 0; kc < 4; ++kc) {
        int byte = (arow*256 + kc*64 + (lane >> 4)*16) ^ ((arow & 7) << 4);
        af[kc] = *reinterpret_cast<const bf16x8*>(reinterpret_cast<const char*>(hid) + byte);
    }
    float part[4] = {0.f, 0.f, 0.f, 0.f};
    #pragma unroll 4
    for (int nt = 0; nt < 16; ++nt) {
        f32x4 acc = f32x4{0.f, 0.f, 0.f, 0.f};
        #pragma unroll
        for (int kc = 0; kc < 4; ++kc) {
            bf16x8 bv = *reinterpret_cast<const bf16x8*>(g_rw1p + ((size_t)(nt*4 + kc)*64 + lane)*8);
            acc = __builtin_amdgcn_mfma_f32_16x16x32_bf16(af[kc], bv, acc, 0, 0, 0);
        }
        int col = nt*16 + ccol;
        float bb = ro_b1[col];
        float wv = ro_w2[col];
        #pragma unroll
        for (int i = 0; i < 4; ++i) part[i] = fmaf(swishf(acc[i] + bb), wv, part[i]);
    }
    // reduce across the 16 lanes of each subgroup (ccol axis)
    #pragma unroll
    for (int m = 1; m < 16; m <<= 1) {
        #pragma unroll
        for (int i = 0; i < 4; ++i) part[i] += __shfl_xor(part[i], m);
    }
    if (ccol == 0) {
        #pragma unroll
        for (int i = 0; i < 4; ++i) {
            int e = e0 + crow + i;
            float sc = part[i] + ro_b2[0];
            int si = nbrs[2*e], di = nbrs[2*e+1];
            #pragma unroll
            for (int d = 0; d < 3; ++d) {
                float fe = sc * g_unitv[3*e+d];
                atomicAdd(&fatom[3*si+d], fe);
                atomicAdd(&fatom[3*di+d], -fe);
            }
        }
    }
}

extern "C" void kernel_launch(void* const* d_in, const int* in_sizes, int n_in,
                              void* d_out, int out_size, void* d_ws, size_t ws_size,
                              hipStream_t stream)
{
    (void)in_sizes; (void)n_in; (void)out_size; (void)d_ws; (void)ws_size;
    const float* xyz    = (const float*)d_in[0];
    const int*   z      = (const int*)  d_in[1];
    const int*   nbrs   = (const int*)  d_in[2];
    const float* emb    = (const float*)d_in[3];
    const float* de_w   = (const float*)d_in[4];
    const float* de_b   = (const float*)d_in[5];
    const float* msg_w1 = (const float*)d_in[6];
    const float* msg_b1 = (const float*)d_in[7];
    const float* msg_w2 = (const float*)d_in[8];
    const float* msg_b2 = (const float*)d_in[9];
    const float* msg_dw = (const float*)d_in[10];
    const float* msg_db = (const float*)d_in[11];
    const float* upd_u  = (const float*)d_in[12];
    const float* upd_v  = (const float*)d_in[13];
    const float* upd_w1 = (const float*)d_in[14];
    const float* upd_b1 = (const float*)d_in[15];
    const float* upd_w2 = (const float*)d_in[16];
    const float* upd_b2 = (const float*)d_in[17];
    const float* edge_w1= (const float*)d_in[18];
    const float* edge_b1= (const float*)d_in[19];
    const float* edge_w2= (const float*)d_in[20];
    const float* edge_b2= (const float*)d_in[21];
    const float* ro_w1  = (const float*)d_in[22];
    const float* ro_b1  = (const float*)d_in[23];
    const float* ro_w2  = (const float*)d_in[24];
    const float* ro_b2  = (const float*)d_in[25];
    float* fout = (float*)d_out;

    void *p_vA=nullptr,*p_vB=nullptr,*p_phi=nullptr,*p_vv=nullptr,*p_stk=nullptr,
         *p_hsm=nullptr,*p_s=nullptr,*p_w1p=nullptr,*p_w2p=nullptr,*p_rw1p=nullptr;
    hipGetSymbolAddress(&p_vA,   HIP_SYMBOL(g_vA));
    hipGetSymbolAddress(&p_vB,   HIP_SYMBOL(g_vB));
    hipGetSymbolAddress(&p_phi,  HIP_SYMBOL(g_phi));
    hipGetSymbolAddress(&p_vv,   HIP_SYMBOL(g_vv));
    hipGetSymbolAddress(&p_stk,  HIP_SYMBOL(g_stk));
    hipGetSymbolAddress(&p_hsm,  HIP_SYMBOL(g_hsm));
    hipGetSymbolAddress(&p_s,    HIP_SYMBOL(g_s));
    hipGetSymbolAddress(&p_w1p,  HIP_SYMBOL(g_w1p));
    hipGetSymbolAddress(&p_w2p,  HIP_SYMBOL(g_w2p));
    hipGetSymbolAddress(&p_rw1p, HIP_SYMBOL(g_rw1p));
    float* vA  = (float*)p_vA;
    float* vB  = (float*)p_vB;
    float* phi = (float*)p_phi;
    float* vv  = (float*)p_vv;
    float* stk = (float*)p_stk;
    float* hsm = (float*)p_hsm;
    float* sft = (float*)p_s;
    unsigned short* w1p  = (unsigned short*)p_w1p;
    unsigned short* w2p  = (unsigned short*)p_w2p;
    unsigned short* rw1p = (unsigned short*)p_rw1p;

    // pack grid MUST cover (K/32)*(N/16)*64 threads
    auto packGrid = [](int K, int N) { return ((K >> 5) * (N >> 4) * 64 + 255) / 256; };

    k_zero <<<(NA*3*FD+255)/256, 256, 0, stream>>>(fout);
    k_geom <<<(NE+255)/256, 256, 0, stream>>>(xyz, nbrs);
    k_embed<<<(NA*FD+255)/256, 256, 0, stream>>>(z, emb);
    k_count<<<(NE+255)/256, 256, 0, stream>>>(nbrs);
    k_scan <<<1, 1024, 0, stream>>>();
    k_fill <<<(NE+255)/256, 256, 0, stream>>>(nbrs);
    for (int l = 0; l < NL; ++l) {
        k_pack<<<packGrid(FD,2*FD), 256, 0, stream>>>(edge_w1 + (size_t)l*FD*2*FD, w1p + (size_t)l*FD*2*FD, FD, 2*FD);
        k_pack<<<packGrid(2*FD,FD), 256, 0, stream>>>(edge_w2 + (size_t)l*2*FD*FD, w2p + (size_t)l*2*FD*FD, 2*FD, FD);
    }
    k_pack<<<packGrid(FD,2*FD), 256, 0, stream>>>(ro_w1, rw1p, FD, 2*FD);

    const int gN  = (NA + BM - 1) / BM;       // 157
    const int g3N = (3*NA + BM - 1) / BM;     // 469
    for (int l = 0; l < NL; ++l) {
        float* vOld = (l & 1) ? vB : vA;
        float* vNew = (l & 1) ? vA : vB;
        const float* mw1 = msg_w1 + (size_t)l*FD*FD;
        const float* mb1 = msg_b1 + (size_t)l*FD;
        const float* mw2 = msg_w2 + (size_t)l*FD*3*FD;
        const float* mb2 = msg_b2 + (size_t)l*3*FD;
        const float* mdw = msg_dw + (size_t)l*NRBF*3*FD;
        const float* mdb = msg_db + (size_t)l*3*FD;
        const float* uu  = upd_u  + (size_t)l*FD*FD;
        const float* uvw = upd_v  + (size_t)l*FD*FD;
        const float* uw1 = upd_w1 + (size_t)l*2*FD*FD;
        const float* ub1 = upd_b1 + (size_t)l*FD;
        const float* uw2 = upd_w2 + (size_t)l*FD*3*FD;
        const float* ub2 = upd_b2 + (size_t)l*3*FD;

        k_gemm<true> <<<dim3(gN,1), 256, 0, stream>>>(sft, mw1, mb1, hsm, NA, FD, FD);
        k_gemm<false><<<dim3(gN,3), 256, 0, stream>>>(hsm, mw2, mb2, phi, NA, FD, 3*FD);
        k_msg<<<NA, FD, 0, stream>>>(nbrs, mdw, mdb, vOld, vNew);
        k_gemm<false><<<dim3(g3N,1), 256, 0, stream>>>(vNew, uu,  nullptr, phi, 3*NA, FD, FD);
        k_gemm<false><<<dim3(g3N,1), 256, 0, stream>>>(vNew, uvw, nullptr, vv,  3*NA, FD, FD);
        k_stack<<<(NA*FD+255)/256, 256, 0, stream>>>();
        k_gemm<true> <<<dim3(gN,1), 256, 0, stream>>>(stk, uw1, ub1, hsm, NA, 2*FD, FD);
        k_gemm<false><<<dim3(gN,3), 256, 0, stream>>>(hsm, uw2, ub2, vOld /*split*/, NA, FD, 3*FD);
        k_apply<<<(NA*FD+255)/256, 256, 0, stream>>>(vOld, vNew);
        k_snap<<<(NA*FD+255)/256, 256, 0, stream>>>(l);
    }
    k_edge_fused<<<NE/64, 256, 0, stream>>>(nbrs, de_w, de_b, edge_b1, edge_b2,
                                            ro_b1, ro_w2, ro_b2, fout);
}

// Round 9
// 2434.943 us; speedup vs baseline: 1.2588x; 1.2588x over previous
//
#include <hip/hip_runtime.h>

#define NA 20000
#define NE 320000
#define FD 128
#define NRBF 20
#define NL 3
#define PI_F 3.14159265358979323846f

typedef __attribute__((ext_vector_type(8))) short bf16x8;
typedef __attribute__((ext_vector_type(4))) float f32x4;

// ---------------- module-static device scratch ----------------
__device__ float g_unitv[NE*3];
__device__ float g_env[NE];
__device__ float g_rbf[NE*NRBF];
__device__ float g_s[NA*FD];
__device__ float g_vA[NA*3*FD];
__device__ float g_vB[NA*3*FD];
__device__ float g_phi[NA*3*FD];        // phi, later reused as u_v
__device__ float g_vv[NA*3*FD];
__device__ float g_stk[NA*2*FD];
__device__ float g_hsm[NA*FD];
__device__ int   g_off[NA+1];
__device__ int   g_cur[NA];
__device__ int   g_eid[NE];
__device__ unsigned short g_sb[NL*NA*FD];        // bf16 s snapshots per layer
// packed bf16 weights (MFMA B-fragment order) — edge path (single bf16, proven)
__device__ unsigned short g_w1p[NL*FD*2*FD];     // edge_w1: K=128,N=256
__device__ unsigned short g_w2p[NL*2*FD*FD];     // edge_w2: K=256,N=128
__device__ unsigned short g_rw1p[FD*2*FD];       // ro_w1:   K=128,N=256
// packed SPLIT bf16 weights (hi+lo) — node path (fp32-like accuracy on MFMA)
__device__ unsigned short g_mw1h[NL*FD*FD],   g_mw1l[NL*FD*FD];     // msg_w1 128x128
__device__ unsigned short g_mw2h[NL*FD*3*FD], g_mw2l[NL*FD*3*FD];   // msg_w2 128x384
__device__ unsigned short g_uuh[NL*FD*FD],    g_uul[NL*FD*FD];      // upd_u  128x128
__device__ unsigned short g_uvh[NL*FD*FD],    g_uvl[NL*FD*FD];      // upd_v  128x128
__device__ unsigned short g_uw1h[NL*2*FD*FD], g_uw1l[NL*2*FD*FD];   // upd_w1 256x128
__device__ unsigned short g_uw2h[NL*FD*3*FD], g_uw2l[NL*FD*3*FD];   // upd_w2 128x384

__device__ __forceinline__ float swishf(float x) { return x / (1.0f + __expf(-x)); }
__device__ __forceinline__ unsigned short f2bf(float x) {
    unsigned int u = __float_as_uint(x);
    unsigned int r = (u + 0x7FFFu + ((u >> 16) & 1u)) >> 16;
    return (unsigned short)r;
}
__device__ __forceinline__ float bf2f(unsigned short u) {
    return __uint_as_float(((unsigned int)u) << 16);
}

// ---------------- geometry ----------------
__global__ __launch_bounds__(256) void k_geom(const float* __restrict__ xyz, const int* __restrict__ nbrs)
{
    int e = blockIdx.x * 256 + threadIdx.x;
    if (e >= NE) return;
    int si = nbrs[2*e], di = nbrs[2*e+1];
    float rx = xyz[3*di+0] - xyz[3*si+0];
    float ry = xyz[3*di+1] - xyz[3*si+1];
    float rz = xyz[3*di+2] - xyz[3*si+2];
    float d2 = rx*rx + ry*ry + rz*rz + 3e-15f;
    float dist = sqrtf(d2);
    float inv = 1.0f / dist;
    g_unitv[3*e+0] = rx*inv;
    g_unitv[3*e+1] = ry*inv;
    g_unitv[3*e+2] = rz*inv;
    g_env[e] = (dist < 5.0f) ? 0.5f*(cosf(PI_F*dist*0.2f) + 1.0f) : 0.0f;
    #pragma unroll
    for (int k = 0; k < NRBF; ++k)
        g_rbf[(size_t)e*NRBF + k] = sinf((float)(k+1) * (PI_F*0.2f) * dist) * inv;
}

// ---------------- init ----------------
__global__ __launch_bounds__(256) void k_embed(const int* __restrict__ z, const float* __restrict__ table)
{
    int idx = blockIdx.x * 256 + threadIdx.x;
    if (idx >= NA * FD) return;
    int n = idx >> 7, f = idx & 127;
    g_s[idx] = table[z[n]*FD + f];
}

__global__ __launch_bounds__(256) void k_zero(float* __restrict__ fout)
{
    int idx = blockIdx.x * 256 + threadIdx.x;
    if (idx < NA*3*FD) g_vA[idx] = 0.f;
    if (idx < NA)      g_cur[idx] = 0;
    if (idx < NA*3)    fout[idx] = 0.f;
}

// ---------------- snapshot s (fp32 -> bf16) after layer l ----------------
__global__ __launch_bounds__(256) void k_snap(int l)
{
    int idx = blockIdx.x * 256 + threadIdx.x;
    if (idx < NA*FD) g_sb[(size_t)l*NA*FD + idx] = f2bf(g_s[idx]);
}

// ---------------- weight pack: row-major W(K,N) -> MFMA B-fragment order ----------------
// REQUIRES grid covering (K>>5)*(N>>4)*64 threads — use packGrid() ONLY.
__global__ __launch_bounds__(256) void k_pack(const float* __restrict__ W, unsigned short* __restrict__ out,
                                              int K, int N)
{
    int idx = blockIdx.x * 256 + threadIdx.x;
    int total = (K >> 5) * (N >> 4) * 64;
    if (idx >= total) return;
    int lane = idx & 63;
    int kc = (idx >> 6) % (K >> 5);
    int nt = (idx >> 6) / (K >> 5);
    int col = nt*16 + (lane & 15);
    int kb  = kc*32 + (lane >> 4) * 8;
    bf16x8 v;
    #pragma unroll
    for (int j = 0; j < 8; ++j) v[j] = (short)f2bf(W[(size_t)(kb + j) * N + col]);
    *reinterpret_cast<bf16x8*>(out + (size_t)idx * 8) = v;
}

// split pack: hi = bf16(w), lo = bf16(w - hi)
__global__ __launch_bounds__(256) void k_pack_split(const float* __restrict__ W,
        unsigned short* __restrict__ hi, unsigned short* __restrict__ lo, int K, int N)
{
    int idx = blockIdx.x * 256 + threadIdx.x;
    int total = (K >> 5) * (N >> 4) * 64;
    if (idx >= total) return;
    int lane = idx & 63;
    int kc = (idx >> 6) % (K >> 5);
    int nt = (idx >> 6) / (K >> 5);
    int col = nt*16 + (lane & 15);
    int kb  = kc*32 + (lane >> 4) * 8;
    bf16x8 vh, vl;
    #pragma unroll
    for (int j = 0; j < 8; ++j) {
        float wv = W[(size_t)(kb + j) * N + col];
        unsigned short h = f2bf(wv);
        vh[j] = (short)h;
        vl[j] = (short)f2bf(wv - bf2f(h));
    }
    *reinterpret_cast<bf16x8*>(hi + (size_t)idx * 8) = vh;
    *reinterpret_cast<bf16x8*>(lo + (size_t)idx * 8) = vl;
}

// ---------------- CSR build ----------------
__global__ __launch_bounds__(256) void k_count(const int* __restrict__ nbrs)
{
    int e = blockIdx.x * 256 + threadIdx.x;
    if (e < NE) atomicAdd(&g_cur[nbrs[2*e]], 1);
}

__global__ __launch_bounds__(1024) void k_scan()
{
    __shared__ int sd[1024];
    __shared__ int sbase;
    int tid = threadIdx.x;
    if (tid == 0) sbase = 0;
    __syncthreads();
    for (int c0 = 0; c0 < NA; c0 += 1024) {
        int i = c0 + tid;
        int x = (i < NA) ? g_cur[i] : 0;
        sd[tid] = x;
        __syncthreads();
        for (int o = 1; o < 1024; o <<= 1) {
            int t = (tid >= o) ? sd[tid - o] : 0;
            __syncthreads();
            sd[tid] += t;
            __syncthreads();
        }
        if (i < NA) { int excl = sbase + sd[tid] - x; g_off[i] = excl; g_cur[i] = excl; }
        __syncthreads();
        if (tid == 0) sbase += sd[1023];
        __syncthreads();
    }
    if (tid == 0) g_off[NA] = sbase;
}

__global__ __launch_bounds__(256) void k_fill(const int* __restrict__ nbrs)
{
    int e = blockIdx.x * 256 + threadIdx.x;
    if (e < NE) { int p = atomicAdd(&g_cur[nbrs[2*e]], 1); g_eid[p] = e; }
}

// ---------------- node GEMM via split-bf16 MFMA ----------------
// C(R,N) = act(A(R,K)@W + bias), W = Whi + Wlo, A = Ahi + Alo (runtime split).
// acc += Ahi*Whi + Alo*Whi + Ahi*Wlo  (AloWlo term ~2^-32, dropped).
// Block = 64 rows, 4 waves x 16 rows; fragments statically indexed.
template<bool SWISH, int K, int N>
__global__ __launch_bounds__(256) void k_ngemm(const float* __restrict__ A,
        const unsigned short* __restrict__ Wh, const unsigned short* __restrict__ Wl,
        const float* __restrict__ bias, float* __restrict__ C, int R)
{
    constexpr int KCN = K >> 5;
    constexpr int NTN = N >> 4;
    int tid = threadIdx.x;
    int lane = tid & 63, w = tid >> 6;
    int r0 = blockIdx.x * 64 + w * 16;
    int arow = r0 + (lane & 15);
    int crow = r0 + ((lane >> 4) << 2);
    int ccol = lane & 15;

    bf16x8 ah[KCN], al[KCN];
    #pragma unroll
    for (int kc = 0; kc < KCN; ++kc) {
        float4 v0 = make_float4(0.f,0.f,0.f,0.f), v1 = make_float4(0.f,0.f,0.f,0.f);
        if (arow < R) {
            const float* ap = A + (size_t)arow*K + kc*32 + (lane >> 4)*8;
            v0 = *reinterpret_cast<const float4*>(ap);
            v1 = *reinterpret_cast<const float4*>(ap + 4);
        }
        float xv[8] = {v0.x, v0.y, v0.z, v0.w, v1.x, v1.y, v1.z, v1.w};
        #pragma unroll
        for (int j = 0; j < 8; ++j) {
            unsigned short h = f2bf(xv[j]);
            ah[kc][j] = (short)h;
            al[kc][j] = (short)f2bf(xv[j] - bf2f(h));
        }
    }
    #pragma unroll 4
    for (int nt = 0; nt < NTN; ++nt) {
        f32x4 acc = f32x4{0.f,0.f,0.f,0.f};
        #pragma unroll
        for (int kc = 0; kc < KCN; ++kc) {
            size_t fo = ((size_t)(nt*KCN + kc)*64 + lane)*8;
            bf16x8 wh = *reinterpret_cast<const bf16x8*>(Wh + fo);
            bf16x8 wl = *reinterpret_cast<const bf16x8*>(Wl + fo);
            acc = __builtin_amdgcn_mfma_f32_16x16x32_bf16(ah[kc], wh, acc, 0, 0, 0);
            acc = __builtin_amdgcn_mfma_f32_16x16x32_bf16(al[kc], wh, acc, 0, 0, 0);
            acc = __builtin_amdgcn_mfma_f32_16x16x32_bf16(ah[kc], wl, acc, 0, 0, 0);
        }
        int col = nt*16 + ccol;
        float bb = bias ? bias[col] : 0.f;
        #pragma unroll
        for (int i = 0; i < 4; ++i) {
            int row = crow + i;
            if (row < R) {
                float x = acc[i] + bb;
                C[(size_t)row*N + col] = SWISH ? swishf(x) : x;
            }
        }
    }
}

// ---------------- message: per-node CSR gather ----------------
__global__ __launch_bounds__(128) void k_msg(
        const int* __restrict__ nbrs,
        const float* __restrict__ dw, const float* __restrict__ db,
        const float* __restrict__ vold, float* __restrict__ vnew)
{
    int n = blockIdx.x;
    int f = threadIdx.x;
    float sacc = 0.f, va0 = 0.f, va1 = 0.f, va2 = 0.f;
    int b = g_off[n], eend = g_off[n+1];
    float db0 = db[f], db1 = db[FD + f], db2 = db[2*FD + f];
    for (int ii = b; ii < eend; ++ii) {
        int e = g_eid[ii];
        int dst = nbrs[2*e+1];
        float ev = g_env[e];
        float rb[NRBF];
        const float4* rp = reinterpret_cast<const float4*>(g_rbf + (size_t)e*NRBF);
        #pragma unroll
        for (int q = 0; q < 5; ++q) { float4 t = rp[q]; rb[4*q]=t.x; rb[4*q+1]=t.y; rb[4*q+2]=t.z; rb[4*q+3]=t.w; }
        float w0 = db0, w1 = db1, w2 = db2;
        #pragma unroll
        for (int k = 0; k < NRBF; ++k) {
            float r = rb[k];
            w0 = fmaf(r, dw[k*3*FD + f],        w0);
            w1 = fmaf(r, dw[k*3*FD + FD + f],   w1);
            w2 = fmaf(r, dw[k*3*FD + 2*FD + f], w2);
        }
        w0 *= ev; w1 *= ev; w2 *= ev;
        const float* pd = g_phi + (size_t)dst*3*FD;
        float p0 = pd[f]        * w0;
        float p1 = pd[FD + f]   * w1;
        float p2 = pd[2*FD + f] * w2;
        sacc += p1;
        float ux = g_unitv[3*e+0], uy = g_unitv[3*e+1], uz = g_unitv[3*e+2];
        const float* vd = vold + (size_t)dst*3*FD;
        va0 = fmaf(p2, ux, fmaf(p0, vd[f],        va0));
        va1 = fmaf(p2, uy, fmaf(p0, vd[FD + f],   va1));
        va2 = fmaf(p2, uz, fmaf(p0, vd[2*FD + f], va2));
    }
    size_t nb = (size_t)n*3*FD;
    vnew[nb + f]        = vold[nb + f]        + va0;
    vnew[nb + FD + f]   = vold[nb + FD + f]   + va1;
    vnew[nb + 2*FD + f] = vold[nb + 2*FD + f] + va2;
    g_s[n*FD + f] += sacc;
}

// ---------------- stack = [s, vnorm(v_v)] ----------------
__global__ __launch_bounds__(256) void k_stack()
{
    int idx = blockIdx.x * 256 + threadIdx.x;
    if (idx >= NA * FD) return;
    int n = idx >> 7, f = idx & 127;
    const float* v = g_vv + (size_t)n*3*FD;
    float a = v[f], b = v[FD + f], c = v[2*FD + f];
    float vn = sqrtf(a*a + b*b + c*c + 3e-15f);
    g_stk[(size_t)n*2*FD + f]      = g_s[idx];
    g_stk[(size_t)n*2*FD + FD + f] = vn;
}

// ---------------- apply update ----------------
__global__ __launch_bounds__(256) void k_apply(const float* __restrict__ split, float* __restrict__ v)
{
    int idx = blockIdx.x * 256 + threadIdx.x;
    if (idx >= NA * FD) return;
    int n = idx >> 7, f = idx & 127;
    const float* sp = split + (size_t)n*3*FD;
    float avv = sp[f], asv = sp[FD + f], ass = sp[2*FD + f];
    size_t nb = (size_t)n*3*FD;
    float dot = 0.f;
    #pragma unroll
    for (int d = 0; d < 3; ++d) {
        float u = g_phi[nb + d*FD + f], w = g_vv[nb + d*FD + f];
        v[nb + d*FD + f] += u * avv;
        dot = fmaf(u, w, dot);
    }
    g_s[idx] += dot * asv + ass;
}

// ================= FUSED edge pipeline (round-5 proven version) =================
// Per block: 64 edges, 4 waves. e-accumulator in VGPRs (8 x f32x4, C-layout)
// across einit -> 3x {cooperative coalesced pair staging -> GEMM1 -> GEMM2}
// -> readout GEMM1 -> dot -> atomic scatter. pairA staged cooperatively
// (coalesced 16B loads) — per-lane scattered gathers were 45% SLOWER (round 8).
__global__ __launch_bounds__(256) void k_edge_fused(
        const int* __restrict__ nbrs,
        const float* __restrict__ de_w, const float* __restrict__ de_b,
        const float* __restrict__ eb1, const float* __restrict__ eb2,
        const float* __restrict__ ro_b1, const float* __restrict__ ro_w2,
        const float* __restrict__ ro_b2, float* __restrict__ fatom)
{
    __shared__ unsigned short pairA[64*128];   // 16 KB
    __shared__ unsigned short hid[64*256];     // 32 KB
    __shared__ int nbrL[128];
    int tid = threadIdx.x;
    int e0 = blockIdx.x * 64;

    float* rbfL  = reinterpret_cast<float*>(pairA);   // 64*20 floats
    float* envL  = rbfL + 64*NRBF;                    // 64 floats
    float* de_wL = reinterpret_cast<float*>(hid);     // 20*128 floats

    if (tid < 128) nbrL[tid] = nbrs[2*e0 + tid];
    #pragma unroll
    for (int i = 0; i < 5; ++i) {
        int j = i*256 + tid;
        if (j < 64*NRBF) rbfL[j] = g_rbf[(size_t)e0*NRBF + j];
    }
    if (tid < 64) envL[tid] = g_env[e0 + tid];
    #pragma unroll
    for (int i = 0; i < 10; ++i) {
        int j = i*256 + tid;
        de_wL[j] = de_w[j];
    }
    __syncthreads();

    int lane = tid & 63, w = tid >> 6;
    int r0 = w * 16;
    int arow = r0 + (lane & 15);
    int crow = r0 + ((lane >> 4) << 2);
    int ccol = lane & 15;

    // ---- einit into acc_e ----
    f32x4 acc_e[8];
    #pragma unroll
    for (int nt = 0; nt < 8; ++nt) acc_e[nt] = f32x4{0.f, 0.f, 0.f, 0.f};
    #pragma unroll 4
    for (int k = 0; k < NRBF; ++k) {
        float rb[4];
        #pragma unroll
        for (int i = 0; i < 4; ++i) rb[i] = rbfL[(crow + i)*NRBF + k];
        #pragma unroll
        for (int nt = 0; nt < 8; ++nt) {
            float wv = de_wL[k*FD + nt*16 + ccol];
            #pragma unroll
            for (int i = 0; i < 4; ++i) acc_e[nt][i] = fmaf(rb[i], wv, acc_e[nt][i]);
        }
    }
    #pragma unroll
    for (int nt = 0; nt < 8; ++nt) {
        float bb = de_b[nt*16 + ccol];
        #pragma unroll
        for (int i = 0; i < 4; ++i) acc_e[nt][i] = (acc_e[nt][i] + bb) * envL[crow + i];
    }

    // ---- 3 edge-MLP layers ----
    for (int l = 0; l < NL; ++l) {
        __syncthreads();
        const unsigned short* sb = g_sb + (size_t)l*NA*FD;
        #pragma unroll
        for (int i = 0; i < 4; ++i) {
            int idx = i*256 + tid;
            int r = idx >> 4, c8 = idx & 15;
            int si = nbrL[2*r], di = nbrL[2*r+1];
            bf16x8 a = *reinterpret_cast<const bf16x8*>(sb + (size_t)si*FD + c8*8);
            bf16x8 b = *reinterpret_cast<const bf16x8*>(sb + (size_t)di*FD + c8*8);
            bf16x8 v;
            #pragma unroll
            for (int j = 0; j < 8; ++j)
                v[j] = (short)f2bf(bf2f((unsigned short)a[j]) + bf2f((unsigned short)b[j]));
            int byte = (r*256 + c8*16) ^ ((r & 7) << 4);
            *reinterpret_cast<bf16x8*>(reinterpret_cast<char*>(pairA) + byte) = v;
        }
        __syncthreads();

        const unsigned short* w1l = g_w1p + (size_t)l*FD*2*FD;
        const unsigned short* w2l = g_w2p + (size_t)l*2*FD*FD;
        const float* b1l = eb1 + (size_t)l*2*FD;
        const float* b2l = eb2 + (size_t)l*FD;

        bf16x8 a1f[4];
        #pragma unroll
        for (int kc = 0; kc < 4; ++kc) {
            int byte = (arow*256 + kc*64 + (lane >> 4)*16) ^ ((arow & 7) << 4);
            a1f[kc] = *reinterpret_cast<const bf16x8*>(reinterpret_cast<const char*>(pairA) + byte);
        }
        #pragma unroll 4
        for (int nt = 0; nt < 16; ++nt) {
            f32x4 acc = f32x4{0.f, 0.f, 0.f, 0.f};
            #pragma unroll
            for (int kc = 0; kc < 4; ++kc) {
                bf16x8 bv = *reinterpret_cast<const bf16x8*>(w1l + ((size_t)(nt*4 + kc)*64 + lane)*8);
                acc = __builtin_amdgcn_mfma_f32_16x16x32_bf16(a1f[kc], bv, acc, 0, 0, 0);
            }
            int col = nt*16 + ccol;
            float bb = b1l[col];
            #pragma unroll
            for (int i = 0; i < 4; ++i) {
                int row = crow + i;
                float h = swishf(acc[i] + bb);
                int byte = (row*512 + col*2) ^ ((row & 7) << 4);
                *reinterpret_cast<unsigned short*>(reinterpret_cast<char*>(hid) + byte) = f2bf(h);
            }
        }
        bf16x8 a2f[8];
        #pragma unroll
        for (int kc = 0; kc < 8; ++kc) {
            int byte = (arow*512 + kc*64 + (lane >> 4)*16) ^ ((arow & 7) << 4);
            a2f[kc] = *reinterpret_cast<const bf16x8*>(reinterpret_cast<const char*>(hid) + byte);
        }
        #pragma unroll 4
        for (int nt = 0; nt < 8; ++nt) {
            f32x4 acc = acc_e[nt];
            #pragma unroll
            for (int kc = 0; kc < 8; ++kc) {
                bf16x8 bv = *reinterpret_cast<const bf16x8*>(w2l + ((size_t)(nt*8 + kc)*64 + lane)*8);
                acc = __builtin_amdgcn_mfma_f32_16x16x32_bf16(a2f[kc], bv, acc, 0, 0, 0);
            }
            float bb = b2l[nt*16 + ccol];
            #pragma unroll
            for (int i = 0; i < 4; ++i) acc[i] += bb;
            acc_e[nt] = acc;
        }
    }

    // ---- readout ----
    #pragma unroll
    for (int nt = 0; nt < 8; ++nt) {
        int col = nt*16 + ccol;
        #pragma unroll
        for (int i = 0; i < 4; ++i) {
            int row = crow + i;
            int byte = (row*256 + col*2) ^ ((row & 7) << 4);
            *reinterpret_cast<unsigned short*>(reinterpret_cast<char*>(pairA) + byte) = f2bf(acc_e[nt][i]);
        }
    }
    bf16x8 a1f[4];
    #pragma unroll
    for (int kc = 0; kc < 4; ++kc) {
        int byte = (arow*256 + kc*64 + (lane >> 4)*16) ^ ((arow & 7) << 4);
        a1f[kc] = *reinterpret_cast<const bf16x8*>(reinterpret_cast<const char*>(pairA) + byte);
    }
    #pragma unroll 4
    for (int nt = 0; nt < 16; ++nt) {
        f32x4 acc = f32x4{0.f, 0.f, 0.f, 0.f};
        #pragma unroll
        for (int kc = 0; kc < 4; ++kc) {
            bf16x8 bv = *reinterpret_cast<const bf16x8*>(g_rw1p + ((size_t)(nt*4 + kc)*64 + lane)*8);
            acc = __builtin_amdgcn_mfma_f32_16x16x32_bf16(a1f[kc], bv, acc, 0, 0, 0);
        }
        int col = nt*16 + ccol;
        float bb = ro_b1[col];
        #pragma unroll
        for (int i = 0; i < 4; ++i) {
            int row = crow + i;
            float h = swishf(acc[i] + bb);
            int byte = (row*512 + col*2) ^ ((row & 7) << 4);
            *reinterpret_cast<unsigned short*>(reinterpret_cast<char*>(hid) + byte) = f2bf(h);
        }
    }
    int erow = r0 + (lane >> 2);
    int kp = lane & 3;
    float part = 0.f;
    #pragma unroll
    for (int cc = 0; cc < 8; ++cc) {
        int byte = (erow*512 + kp*128 + cc*16) ^ ((erow & 7) << 4);
        bf16x8 hv = *reinterpret_cast<const bf16x8*>(reinterpret_cast<const char*>(hid) + byte);
        const float* wp = ro_w2 + kp*64 + cc*8;
        #pragma unroll
        for (int j = 0; j < 8; ++j)
            part = fmaf(bf2f((unsigned short)hv[j]), wp[j], part);
    }
    part += __shfl_xor(part, 1);
    part += __shfl_xor(part, 2);
    if (kp == 0) {
        int e = e0 + erow;
        float sc = part + ro_b2[0];
        int si = nbrL[2*erow], di = nbrL[2*erow+1];
        #pragma unroll
        for (int d = 0; d < 3; ++d) {
            float fe = sc * g_unitv[3*e+d];
            atomicAdd(&fatom[3*si+d], fe);
            atomicAdd(&fatom[3*di+d], -fe);
        }
    }
}

extern "C" void kernel_launch(void* const* d_in, const int* in_sizes, int n_in,
                              void* d_out, int out_size, void* d_ws, size_t ws_size,
                              hipStream_t stream)
{
    (void)in_sizes; (void)n_in; (void)out_size; (void)d_ws; (void)ws_size;
    const float* xyz    = (const float*)d_in[0];
    const int*   z      = (const int*)  d_in[1];
    const int*   nbrs   = (const int*)  d_in[2];
    const float* emb    = (const float*)d_in[3];
    const float* de_w   = (const float*)d_in[4];
    const float* de_b   = (const float*)d_in[5];
    const float* msg_w1 = (const float*)d_in[6];
    const float* msg_b1 = (const float*)d_in[7];
    const float* msg_w2 = (const float*)d_in[8];
    const float* msg_b2 = (const float*)d_in[9];
    const float* msg_dw = (const float*)d_in[10];
    const float* msg_db = (const float*)d_in[11];
    const float* upd_u  = (const float*)d_in[12];
    const float* upd_v  = (const float*)d_in[13];
    const float* upd_w1 = (const float*)d_in[14];
    const float* upd_b1 = (const float*)d_in[15];
    const float* upd_w2 = (const float*)d_in[16];
    const float* upd_b2 = (const float*)d_in[17];
    const float* edge_w1= (const float*)d_in[18];
    const float* edge_b1= (const float*)d_in[19];
    const float* edge_w2= (const float*)d_in[20];
    const float* edge_b2= (const float*)d_in[21];
    const float* ro_w1  = (const float*)d_in[22];
    const float* ro_b1  = (const float*)d_in[23];
    const float* ro_w2  = (const float*)d_in[24];
    const float* ro_b2  = (const float*)d_in[25];
    float* fout = (float*)d_out;

    void *pv;
    auto sym = [&](const void* s) { hipGetSymbolAddress(&pv, s); return pv; };
    float* vA  = (float*)sym(HIP_SYMBOL(g_vA));
    float* vB  = (float*)sym(HIP_SYMBOL(g_vB));
    float* phi = (float*)sym(HIP_SYMBOL(g_phi));
    float* vv  = (float*)sym(HIP_SYMBOL(g_vv));
    float* stk = (float*)sym(HIP_SYMBOL(g_stk));
    float* hsm = (float*)sym(HIP_SYMBOL(g_hsm));
    float* sft = (float*)sym(HIP_SYMBOL(g_s));
    unsigned short* w1p  = (unsigned short*)sym(HIP_SYMBOL(g_w1p));
    unsigned short* w2p  = (unsigned short*)sym(HIP_SYMBOL(g_w2p));
    unsigned short* rw1p = (unsigned short*)sym(HIP_SYMBOL(g_rw1p));
    unsigned short* mw1h = (unsigned short*)sym(HIP_SYMBOL(g_mw1h));
    unsigned short* mw1l = (unsigned short*)sym(HIP_SYMBOL(g_mw1l));
    unsigned short* mw2h = (unsigned short*)sym(HIP_SYMBOL(g_mw2h));
    unsigned short* mw2l = (unsigned short*)sym(HIP_SYMBOL(g_mw2l));
    unsigned short* uuh  = (unsigned short*)sym(HIP_SYMBOL(g_uuh));
    unsigned short* uul  = (unsigned short*)sym(HIP_SYMBOL(g_uul));
    unsigned short* uvh  = (unsigned short*)sym(HIP_SYMBOL(g_uvh));
    unsigned short* uvl  = (unsigned short*)sym(HIP_SYMBOL(g_uvl));
    unsigned short* uw1h = (unsigned short*)sym(HIP_SYMBOL(g_uw1h));
    unsigned short* uw1l = (unsigned short*)sym(HIP_SYMBOL(g_uw1l));
    unsigned short* uw2h = (unsigned short*)sym(HIP_SYMBOL(g_uw2h));
    unsigned short* uw2l = (unsigned short*)sym(HIP_SYMBOL(g_uw2l));

    // pack grid MUST cover (K/32)*(N/16)*64 threads
    auto packGrid = [](int K, int N) { return ((K >> 5) * (N >> 4) * 64 + 255) / 256; };

    k_zero <<<(NA*3*FD+255)/256, 256, 0, stream>>>(fout);
    k_geom <<<(NE+255)/256, 256, 0, stream>>>(xyz, nbrs);
    k_embed<<<(NA*FD+255)/256, 256, 0, stream>>>(z, emb);
    k_count<<<(NE+255)/256, 256, 0, stream>>>(nbrs);
    k_scan <<<1, 1024, 0, stream>>>();
    k_fill <<<(NE+255)/256, 256, 0, stream>>>(nbrs);
    for (int l = 0; l < NL; ++l) {
        k_pack<<<packGrid(FD,2*FD), 256, 0, stream>>>(edge_w1 + (size_t)l*FD*2*FD, w1p + (size_t)l*FD*2*FD, FD, 2*FD);
        k_pack<<<packGrid(2*FD,FD), 256, 0, stream>>>(edge_w2 + (size_t)l*2*FD*FD, w2p + (size_t)l*2*FD*FD, 2*FD, FD);
        k_pack_split<<<packGrid(FD,FD),   256, 0, stream>>>(msg_w1 + (size_t)l*FD*FD,   mw1h + (size_t)l*FD*FD,   mw1l + (size_t)l*FD*FD,   FD, FD);
        k_pack_split<<<packGrid(FD,3*FD), 256, 0, stream>>>(msg_w2 + (size_t)l*FD*3*FD, mw2h + (size_t)l*FD*3*FD, mw2l + (size_t)l*FD*3*FD, FD, 3*FD);
        k_pack_split<<<packGrid(FD,FD),   256, 0, stream>>>(upd_u  + (size_t)l*FD*FD,   uuh  + (size_t)l*FD*FD,   uul  + (size_t)l*FD*FD,   FD, FD);
        k_pack_split<<<packGrid(FD,FD),   256, 0, stream>>>(upd_v  + (size_t)l*FD*FD,   uvh  + (size_t)l*FD*FD,   uvl  + (size_t)l*FD*FD,   FD, FD);
        k_pack_split<<<packGrid(2*FD,FD), 256, 0, stream>>>(upd_w1 + (size_t)l*2*FD*FD, uw1h + (size_t)l*2*FD*FD, uw1l + (size_t)l*2*FD*FD, 2*FD, FD);
        k_pack_split<<<packGrid(FD,3*FD), 256, 0, stream>>>(upd_w2 + (size_t)l*FD*3*FD, uw2h + (size_t)l*FD*3*FD, uw2l + (size_t)l*FD*3*FD, FD, 3*FD);
    }
    k_pack<<<packGrid(FD,2*FD), 256, 0, stream>>>(ro_w1, rw1p, FD, 2*FD);

    const int gN  = (NA + 63) / 64;       // 313
    const int g3N = (3*NA + 63) / 64;     // 938
    for (int l = 0; l < NL; ++l) {
        float* vOld = (l & 1) ? vB : vA;
        float* vNew = (l & 1) ? vA : vB;
        const float* mb1 = msg_b1 + (size_t)l*FD;
        const float* mb2 = msg_b2 + (size_t)l*3*FD;
        const float* mdw = msg_dw + (size_t)l*NRBF*3*FD;
        const float* mdb = msg_db + (size_t)l*3*FD;
        const float* ub1 = upd_b1 + (size_t)l*FD;
        const float* ub2 = upd_b2 + (size_t)l*3*FD;

        k_ngemm<true,128,128> <<<gN, 256, 0, stream>>>(sft, mw1h + (size_t)l*FD*FD, mw1l + (size_t)l*FD*FD, mb1, hsm, NA);
        k_ngemm<false,128,384><<<gN, 256, 0, stream>>>(hsm, mw2h + (size_t)l*FD*3*FD, mw2l + (size_t)l*FD*3*FD, mb2, phi, NA);
        k_msg<<<NA, FD, 0, stream>>>(nbrs, mdw, mdb, vOld, vNew);
        k_ngemm<false,128,128><<<g3N, 256, 0, stream>>>(vNew, uuh + (size_t)l*FD*FD, uul + (size_t)l*FD*FD, nullptr, phi, 3*NA);
        k_ngemm<false,128,128><<<g3N, 256, 0, stream>>>(vNew, uvh + (size_t)l*FD*FD, uvl + (size_t)l*FD*FD, nullptr, vv, 3*NA);
        k_stack<<<(NA*FD+255)/256, 256, 0, stream>>>();
        k_ngemm<true,256,128> <<<gN, 256, 0, stream>>>(stk, uw1h + (size_t)l*2*FD*FD, uw1l + (size_t)l*2*FD*FD, ub1, hsm, NA);
        k_ngemm<false,128,384><<<gN, 256, 0, stream>>>(hsm, uw2h + (size_t)l*FD*3*FD, uw2l + (size_t)l*FD*3*FD, ub2, vOld /*split*/, NA);
        k_apply<<<(NA*FD+255)/256, 256, 0, stream>>>(vOld, vNew);
        k_snap<<<(NA*FD+255)/256, 256, 0, stream>>>(l);
    }
    k_edge_fused<<<NE/64, 256, 0, stream>>>(nbrs, de_w, de_b, edge_b1, edge_b2,
                                            ro_b1, ro_w2, ro_b2, fout);
}